// Round 3
// baseline (134.850 us; speedup 1.0000x reference)
//
#include <hip/hip_runtime.h>

// B=16384 samples, F=256 features, T=512 trees, D=7 levels below root, C=4 outputs
#define BB 16384
#define FF 256
#define TT 512
#define DD 7

// LDS x row stride (floats), padded so bank = (s + f) % 32.
#define XS 257

constexpr int S_   = 32;        // samples per block (LDS: 32*257*4 = 32.9 KB -> 4 blocks/CU)
constexpr int NT_  = 512;       // threads/block = 8 waves; 1024 blocks -> 32 waves/CU
constexpr int NTG  = NT_ / S_;  // 16 tree-groups per block
constexpr int HT   = TT / 2;    // 256 trees per block (tree-half split across blockIdx.y)
constexpr int TPT  = HT / NTG;  // 16 trees per thread
constexpr int NP   = 8;         // concurrent tree chains per thread (ILP)
constexpr int NJ   = TPT / NP;  // 2 outer iterations

// One dispatch. Nodes/biases/leaves read straight from L2 (lanes of a half-wave
// share the tree, so a level-l gather spans <= 2^l consecutive entries). x lives
// in LDS with padded stride. Two tree-half blocks combine via atomicAdd.
__global__ __launch_bounds__(NT_, 8)
void tree_traverse_kernel(const float* __restrict__ x,
                          const int*   __restrict__ root_nodes,
                          const float* __restrict__ root_biases,
                          const int*   __restrict__ nodes_flat,
                          const float* __restrict__ biases_flat,
                          const float* __restrict__ leaf_nodes,
                          float*       __restrict__ out)
{
    __shared__ float x_s[S_ * XS];

    const int tid = threadIdx.x;
    const int s   = tid & (S_ - 1);          // lane's sample within block
    const int tg  = tid / S_;                // tree-group (16 per block)
    const int s0  = blockIdx.x * S_;
    const int h0  = blockIdx.y * HT;         // first tree of this block's half

    // ---- stage x rows: float4 global loads, scalar LDS stores (padded stride) ----
    {
        const float4* xg = (const float4*)(x + (size_t)s0 * FF);
        const int r = tid >> 4;              // row 0..31
        const int v = tid & 15;              // 16 of 64 float4 per row
        #pragma unroll
        for (int c = 0; c < 4; ++c) {
            const float4 q = xg[r * (FF / 4) + v + 16 * c];
            const int base = r * XS + (v + 16 * c) * 4;
            x_s[base + 0] = q.x; x_s[base + 1] = q.y;
            x_s[base + 2] = q.z; x_s[base + 3] = q.w;
        }
    }
    __syncthreads();

    const int xb = s * XS;
    const float4* leaf4 = (const float4*)leaf_nodes;
    float a0 = 0.f, a1 = 0.f, a2 = 0.f, a3 = 0.f;

    #pragma unroll 1
    for (int j = 0; j < NJ; ++j) {
        const int tbase = h0 + tg * TPT + j * NP;

        // ---- root level ----
        int p[NP];
        #pragma unroll
        for (int k = 0; k < NP; ++k) {
            const int t  = tbase + k;
            const int rn = root_nodes[t];
            const float rb = root_biases[t];
            p[k] = (x_s[xb + rn] < rb) ? 1 : 0;
        }

        // ---- levels 1..D: NP independent chains ----
        #pragma unroll
        for (int l = 1; l <= DD; ++l) {
            const int lbase = TT * ((1 << l) - 2);
            #pragma unroll
            for (int k = 0; k < NP; ++k) {
                const int t = tbase + k;
                const int e = lbase + (t << l) + p[k];
                const int   fi = nodes_flat[e];
                const float bi = biases_flat[e];
                const float ft = x_s[xb + fi];
                p[k] = 2 * p[k] + ((ft < bi) ? 1 : 0);
            }
        }

        // ---- leaf gather (L2) + accumulate ----
        #pragma unroll
        for (int k = 0; k < NP; ++k) {
            const int t = tbase + k;
            const float4 lf = leaf4[(t << (DD + 1)) + p[k]];
            a0 += lf.x; a1 += lf.y; a2 += lf.z; a3 += lf.w;
        }
    }

    // ---- reduce 16 tree-group partials per sample, then atomicAdd (2 contenders) ----
    __syncthreads();
    float* red = x_s;    // 512*4 = 2048 floats, fits in x_s region
    red[tid * 4 + 0] = a0; red[tid * 4 + 1] = a1;
    red[tid * 4 + 2] = a2; red[tid * 4 + 3] = a3;
    __syncthreads();
    if (tid < S_ * 4) {
        const int smp = tid >> 2;            // sample 0..31
        const int c   = tid & 3;             // component 0..3
        float o = 0.f;
        #pragma unroll
        for (int g = 0; g < NTG; ++g)
            o += red[((g << 5) + smp) * 4 + c];
        atomicAdd(out + (size_t)(s0 + smp) * 4 + c, o);
    }
}

extern "C" void kernel_launch(void* const* d_in, const int* in_sizes, int n_in,
                              void* d_out, int out_size, void* d_ws, size_t ws_size,
                              hipStream_t stream) {
    const float* x           = (const float*)d_in[0];
    const int*   root_nodes  = (const int*)  d_in[1];
    const float* root_biases = (const float*)d_in[2];
    // d_in[3] = tree_indices = 2*t, folded into index math
    const int*   nodes_flat  = (const int*)  d_in[4];
    const float* biases_flat = (const float*)d_in[5];
    const float* leaf_nodes  = (const float*)d_in[6];
    float*       out         = (float*)d_out;

    // zero accumulation target (d_out is poisoned before every launch)
    (void)hipMemsetAsync(d_out, 0, (size_t)out_size * sizeof(float), stream);

    dim3 grid(BB / S_, 2);
    tree_traverse_kernel<<<grid, NT_, 0, stream>>>(
        x, root_nodes, root_biases, nodes_flat, biases_flat, leaf_nodes, out);
}

// Round 4
// 115.380 us; speedup vs baseline: 1.1687x; 1.1687x over previous
//
#include <hip/hip_runtime.h>

// B=16384 samples, F=256 features, T=512 trees, D=7 levels below root, C=4 outputs
#define BB 16384
#define FF 256
#define TT 512
#define DD 7

constexpr int S_   = 64;         // samples per block; one wave == one sample-group
constexpr int NT_  = 1024;       // 16 waves/block, grid=256 -> 1 block/CU, 16 waves/CU
constexpr int NTG  = NT_ / S_;   // 16 tree-groups (one per wave)
constexpr int TPT  = TT / NTG;   // 32 trees per thread
constexpr int NP   = 8;          // concurrent tree chains per thread (ILP)
constexpr int NJ   = TPT / NP;   // 4 outer iterations
constexpr int NPACK = TT * ((1 << (DD + 1)) - 2);  // 130048 internal nodes
constexpr int NPALL = NPACK + TT;                  // + packed roots

// Pack (feat, bias) into int2: one 8B gather per traversal step instead of two
// 4B gathers (halves VMEM instrs + dependent loads; saves lines at low levels).
__global__ void pack_nodes_kernel(const int* __restrict__ nf,
                                  const float* __restrict__ bf,
                                  const int* __restrict__ rn,
                                  const float* __restrict__ rb,
                                  int2* __restrict__ tp) {
    int i = blockIdx.x * 256 + threadIdx.x;
    if (i < NPACK) tp[i] = make_int2(nf[i], __float_as_int(bf[i]));
    else if (i < NPALL) {
        int t = i - NPACK;
        tp[i] = make_int2(rn[t], __float_as_int(rb[t]));
    }
}

// x rows live in LDS, XOR-swizzled (element f of row s at f ^ (s&31)) so
// bank = (f%32)^(s%32): shared-feature reads are conflict-free, no padding.
// Nodes/leaves gathered from L2; all 64 lanes of a wave share one tree, so a
// level-l gather spans <= 2^l consecutive int2 entries.
template<bool PACKED>
__global__ __launch_bounds__(NT_, 4)
void tree_traverse_kernel(const float* __restrict__ x,
                          const int*   __restrict__ root_nodes,
                          const float* __restrict__ root_biases,
                          const int*   __restrict__ nodes_flat,
                          const float* __restrict__ biases_flat,
                          const float* __restrict__ leaf_nodes,
                          const int2*  __restrict__ tp,
                          float*       __restrict__ out)
{
    extern __shared__ float x_s[];   // 64 rows * 256 floats = 64 KB

    const int tid = threadIdx.x;
    const int s   = tid & (S_ - 1);    // lane's sample (wave covers all 64)
    const int tg  = tid >> 6;          // tree-group == wave id
    const int s0  = blockIdx.x * S_;

    // ---- stage x rows: float4 global loads, swizzled scalar LDS stores ----
    {
        const float4* xg = (const float4*)(x + (size_t)s0 * FF);
        const int r  = tid >> 4;       // row 0..63
        const int v  = tid & 15;       // 16 of 64 float4 per row
        const int rz = r & 31;
        float* row = x_s + (r << 8);
        #pragma unroll
        for (int c = 0; c < 4; ++c) {
            const float4 q = xg[r * (FF / 4) + v + 16 * c];
            const int f0 = (v + 16 * c) * 4;
            row[(f0 + 0) ^ rz] = q.x;
            row[(f0 + 1) ^ rz] = q.y;
            row[(f0 + 2) ^ rz] = q.z;
            row[(f0 + 3) ^ rz] = q.w;
        }
    }
    __syncthreads();

    const int   xb = s << 8;
    const int   sz = s & 31;
    const float4* leaf4 = (const float4*)leaf_nodes;
    float a0 = 0.f, a1 = 0.f, a2 = 0.f, a3 = 0.f;

    #pragma unroll 1
    for (int j = 0; j < NJ; ++j) {
        const int tbase = tg * TPT + j * NP;

        // ---- root level (wave-uniform addresses -> broadcast loads) ----
        int p[NP];
        #pragma unroll
        for (int k = 0; k < NP; ++k) {
            const int t = tbase + k;
            int rn; float rbv;
            if (PACKED) {
                const int2 nb = tp[NPACK + t];
                rn = nb.x; rbv = __int_as_float(nb.y);
            } else {
                rn = root_nodes[t]; rbv = root_biases[t];
            }
            p[k] = (x_s[xb | (rn ^ sz)] < rbv) ? 1 : 0;
        }

        // ---- levels 1..D: NP independent chains per level ----
        #pragma unroll
        for (int l = 1; l <= DD; ++l) {
            const int lbase = TT * ((1 << l) - 2);
            #pragma unroll
            for (int k = 0; k < NP; ++k) {
                const int t = tbase + k;
                const int e = lbase + (t << l) + p[k];
                int fi; float bi;
                if (PACKED) {
                    const int2 nb = tp[e];
                    fi = nb.x; bi = __int_as_float(nb.y);
                } else {
                    fi = nodes_flat[e]; bi = biases_flat[e];
                }
                const float ft = x_s[xb | (fi ^ sz)];
                p[k] = 2 * p[k] + ((ft < bi) ? 1 : 0);
            }
        }

        // ---- leaf gather (L2) + accumulate ----
        #pragma unroll
        for (int k = 0; k < NP; ++k) {
            const int t = tbase + k;
            const float4 lf = leaf4[(t << (DD + 1)) + p[k]];
            a0 += lf.x; a1 += lf.y; a2 += lf.z; a3 += lf.w;
        }
    }

    // ---- reduce 16 tree-group partials per sample (overlay on x_s) ----
    __syncthreads();
    ((float4*)x_s)[tid] = make_float4(a0, a1, a2, a3);  // 16 KB of the 64 KB
    __syncthreads();
    if (tid < S_ * 4) {                 // 256 threads: sample=tid>>2, comp=tid&3
        float o = 0.f;
        #pragma unroll
        for (int g = 0; g < NTG; ++g)
            o += x_s[(g << 8) + tid];   // addr = g*256 + tid: conflict-free
        out[(size_t)s0 * 4 + tid] = o;  // fully coalesced 1 KB store
    }
}

extern "C" void kernel_launch(void* const* d_in, const int* in_sizes, int n_in,
                              void* d_out, int out_size, void* d_ws, size_t ws_size,
                              hipStream_t stream) {
    const float* x           = (const float*)d_in[0];
    const int*   root_nodes  = (const int*)  d_in[1];
    const float* root_biases = (const float*)d_in[2];
    // d_in[3] = tree_indices = 2*t, folded into index math
    const int*   nodes_flat  = (const int*)  d_in[4];
    const float* biases_flat = (const float*)d_in[5];
    const float* leaf_nodes  = (const float*)d_in[6];
    float*       out         = (float*)d_out;

    constexpr size_t LDS_BYTES = (size_t)S_ * FF * sizeof(float);  // 65536
    const bool packed = ws_size >= (size_t)NPALL * sizeof(int2);
    int2* tp = (int2*)d_ws;

    if (packed) {
        pack_nodes_kernel<<<(NPALL + 255) / 256, 256, 0, stream>>>(
            nodes_flat, biases_flat, root_nodes, root_biases, tp);
        tree_traverse_kernel<true><<<BB / S_, NT_, LDS_BYTES, stream>>>(
            x, root_nodes, root_biases, nodes_flat, biases_flat, leaf_nodes, tp, out);
    } else {
        tree_traverse_kernel<false><<<BB / S_, NT_, LDS_BYTES, stream>>>(
            x, root_nodes, root_biases, nodes_flat, biases_flat, leaf_nodes, tp, out);
    }
}